// Round 4
// baseline (63.993 us; speedup 1.0000x reference)
//
#include <hip/hip_runtime.h>

// Q_RUNLayer_Hybrid: monarch(blockdiag R -> stride perm -> blockdiag L) + bias
// -> LayerNorm -> h + (h@Wd)@Wu -> sin/cos reupload (3) -> [PROJ,6]@Wp.T+bp
// Fused MFMA implementation, 32 tokens/wg (weight frags amortized over 2
// token-rows), split-bf16 via v_cvt_pk_bf16_f32, LayerNorm folded into
// down-proj (Wd' = diag(gamma)Wd; fixup with B=gamma@Wd, C=beta@Wd),
// packed per-p parameter table with 1/(2pi)-folded thetas/phis.

typedef __attribute__((ext_vector_type(8))) short bf16x8;
typedef __attribute__((ext_vector_type(4))) float f32x4;

#define PITCH 1032            // ushorts per plane row (1024 + 8 pad)
#define TOK 32                // tokens per workgroup
#define DPITCH 68             // floats per dbuf row
#define SMEM_BYTES 151808     // 2*32*1032*2 + 2*32*68*4 + 512*4 + 64*4

__device__ __forceinline__ unsigned short f2bf(float f) {
    unsigned u = __float_as_uint(f);
    u = (u + 0x7FFFu + ((u >> 16) & 1u)) >> 16;   // RNE f32 -> bf16
    return (unsigned short)u;
}
__device__ __forceinline__ float bf2f(unsigned short h) {
    return __uint_as_float(((unsigned)h) << 16);
}
__device__ __forceinline__ unsigned cvt_pk_bf16(float a, float b) {
    unsigned r;                                   // lo16 = bf16(a), hi16 = bf16(b)
    asm("v_cvt_pk_bf16_f32 %0, %1, %2" : "=v"(r) : "v"(a), "v"(b));
    return r;
}
// split (a,b) -> packed hi u32 + packed lo u32 (lo = exact residual, re-rounded)
__device__ __forceinline__ void split2(float a, float b, unsigned &H, unsigned &L) {
    H = cvt_pk_bf16(a, b);
    const float ha = __uint_as_float(H << 16);
    const float hb = __uint_as_float(H & 0xFFFF0000u);
    L = cvt_pk_bf16(a - ha, b - hb);
}
__device__ __forceinline__ f32x4 MFMA(bf16x8 a, bf16x8 b, f32x4 c) {
    return __builtin_amdgcn_mfma_f32_16x16x32_bf16(a, b, c, 0, 0, 0);
}

// ---------------------------------------------------------------------------
// Pack weights into MFMA fragment order (hi/lo bf16), one 64x64 block per wg.
// blk 0..15 = R[b], 16..31 = L[c], 32..47 = Wd' = diag(gamma)Wd k-block,
// 48..63 = Wu n-block.
// blk 64: bcf[0..63] = B = gamma@Wd, bcf[64..127] = C = beta@Wd,
//         bcf[128 + p*8 + {0..7}] = {gamma, beta, th0',th1',th2', ph0',ph1',ph2'}
//         with th'/ph' pre-multiplied by 1/(2*pi)  (for v_sin/v_cos).
// Frag addressing (ushorts): blk*8192 + ((kk*4+nt)*2+comp)*512 + lane*8
// element v of lane l:  M[kk*32 + (l>>4)*8 + v][nt*16 + (l&15)]
// ---------------------------------------------------------------------------
__global__ __launch_bounds__(256) void pack_weights(
    const float* __restrict__ R, const float* __restrict__ L,
    const float* __restrict__ Wd, const float* __restrict__ Wu,
    const float* __restrict__ gamma, const float* __restrict__ beta,
    const float* __restrict__ thetas, const float* __restrict__ phis,
    unsigned short* __restrict__ wsp)
{
    const int blk = blockIdx.x;
    const int tid = threadIdx.x;
    if (blk == 64) {
        float* bc = (float*)(wsp + (size_t)64 * 8192);
        const float INV2PI = 0.15915494309189535f;
        for (int i = tid; i < 1024; i += 256) {
            float* t = bc + 128 + i * 8;
            t[0] = gamma[i];                 t[1] = beta[i];
            t[2] = thetas[i] * INV2PI;       t[3] = thetas[1024 + i] * INV2PI;
            t[4] = thetas[2048 + i] * INV2PI;
            t[5] = phis[i] * INV2PI;         t[6] = phis[1024 + i] * INV2PI;
            t[7] = phis[2048 + i] * INV2PI;
        }
        __shared__ float red[8][64];
        const int r = tid & 63, part = tid >> 6;
        float sb = 0.f, sc = 0.f;
        for (int c = part * 256; c < part * 256 + 256; ++c) {
            const float w = Wd[(size_t)c * 64 + r];
            sb += gamma[c] * w;
            sc += beta[c] * w;
        }
        red[part][r] = sb; red[part + 4][r] = sc;
        __syncthreads();
        if (part == 0) {
            bc[r]      = red[0][r] + red[1][r] + red[2][r] + red[3][r];
            bc[64 + r] = red[4][r] + red[5][r] + red[6][r] + red[7][r];
        }
        return;
    }
    unsigned short* dst = wsp + (size_t)blk * 8192;
    for (int it = 0; it < 4; ++it) {
        const int slot = tid + it * 256;
        const int fragidx = slot >> 6;
        const int l = slot & 63;
        const int kk = fragidx >> 3;
        const int nt = (fragidx >> 1) & 3;
        const int comp = fragidx & 1;
        const int g = l >> 4, r16 = l & 15;
        const int j = nt * 16 + r16;
        bf16x8 s;
        #pragma unroll
        for (int v = 0; v < 8; ++v) {
            const int k = kk * 32 + g * 8 + v;
            float w;
            if (blk < 16)      w = R[(size_t)blk * 4096 + k * 64 + j];
            else if (blk < 32) w = L[(size_t)(blk - 16) * 4096 + k * 64 + j];
            else if (blk < 48) {
                const int kglob = (blk - 32) * 64 + k;
                w = gamma[kglob] * Wd[(size_t)kglob * 64 + j];
            } else             w = Wu[(size_t)k * 1024 + (blk - 48) * 64 + j];
            unsigned short hi = f2bf(w);
            unsigned short bits = (comp == 0) ? hi : f2bf(w - bf2f(hi));
            s[v] = (short)bits;
        }
        *(bf16x8*)(dst + fragidx * 512 + l * 8) = s;
    }
}

// ---------------------------------------------------------------------------
// Fused main kernel. 512 threads (8 waves), 32 tokens per workgroup (2 rows
// of 16; each wave serves both rows -> weight fragments amortized 2x).
// Wave w: grp = w>>2 in {0,1} (splits block/K loops), ntw = w&3.
// ---------------------------------------------------------------------------
__global__ __launch_bounds__(512, 2) void qrun_main(
    const float* __restrict__ x, const float* __restrict__ bias,
    const float* __restrict__ Wp, const float* __restrict__ bpv,
    const unsigned short* __restrict__ wpk, float* __restrict__ out)
{
    extern __shared__ char smem[];
    unsigned short* hiP = (unsigned short*)smem;          // [32][PITCH]
    unsigned short* loP = hiP + TOK * PITCH;              // [32][PITCH]
    float* dbuf = (float*)(loP + TOK * PITCH);            // [2][32][DPITCH]
    float* lnpart = dbuf + 2 * TOK * DPITCH;              // [8][2][16][2]
    float* statsR = lnpart + 512;                         // [32][2]

    const int tid = threadIdx.x;
    const int wave = tid >> 6, lane = tid & 63;
    const int g = lane >> 4, r16 = lane & 15;
    const int grp = wave >> 2, ntw = wave & 3;
    const size_t n0 = (size_t)blockIdx.x * TOK;

    // ---- phase 0: load x tile, split to hi/lo bf16 planes ----
    {
        const float* xb = x + n0 * 1024;
        #pragma unroll
        for (int it = 0; it < 8; ++it) {
            const int base = (it * 512 + tid) * 8;
            const int row = base >> 10, col = base & 1023;
            const float4 f0 = *(const float4*)(xb + base);
            const float4 f1 = *(const float4*)(xb + base + 4);
            unsigned H0, L0, H1, L1, H2, L2, H3, L3;
            split2(f0.x, f0.y, H0, L0);
            split2(f0.z, f0.w, H1, L1);
            split2(f1.x, f1.y, H2, L2);
            split2(f1.z, f1.w, H3, L3);
            *(uint4*)(hiP + row * PITCH + col) = make_uint4(H0, H1, H2, H3);
            *(uint4*)(loP + row * PITCH + col) = make_uint4(L0, L1, L2, L3);
        }
    }
    __syncthreads();

    // ---- phase 1: monarch stage 1 (x @ R[b]); weights reused across tr ----
    f32x4 acc1[8][2];
    #pragma unroll
    for (int bi = 0; bi < 8; ++bi) {
        const int b = grp * 8 + bi;
        const unsigned short* wb = wpk + (size_t)b * 8192;
        bf16x8 Bh0 = *(const bf16x8*)(wb + ((0*4+ntw)*2+0)*512 + lane*8);
        bf16x8 Bl0 = *(const bf16x8*)(wb + ((0*4+ntw)*2+1)*512 + lane*8);
        bf16x8 Bh1 = *(const bf16x8*)(wb + ((1*4+ntw)*2+0)*512 + lane*8);
        bf16x8 Bl1 = *(const bf16x8*)(wb + ((1*4+ntw)*2+1)*512 + lane*8);
        const int ca = b * 64 + g * 8;
        #pragma unroll
        for (int tr = 0; tr < 2; ++tr) {
            const int rowA = (tr * 16 + r16) * PITCH;
            bf16x8 Ah0 = *(const bf16x8*)(hiP + rowA + ca);
            bf16x8 Al0 = *(const bf16x8*)(loP + rowA + ca);
            bf16x8 Ah1 = *(const bf16x8*)(hiP + rowA + ca + 32);
            bf16x8 Al1 = *(const bf16x8*)(loP + rowA + ca + 32);
            f32x4 a = {0.f, 0.f, 0.f, 0.f};
            a = MFMA(Ah0, Bh0, a); a = MFMA(Ah0, Bl0, a); a = MFMA(Al0, Bh0, a);
            a = MFMA(Ah1, Bh1, a); a = MFMA(Ah1, Bl1, a); a = MFMA(Al1, Bh1, a);
            acc1[bi][tr] = a;
        }
    }
    __syncthreads();   // all stage-1 reads complete before permuted overwrite

    // permuted write: D col (b*64+ntw*16+r16) -> dest col; the 8 bi land on 8
    // consecutive columns => b128 write. g-field XOR-swizzled by (c'&3).
    {
        const int Cw = (ntw * 4 + (r16 >> 2)) * 64 + ((r16 >> 1) & 1) * 32
                     + (((grp + 2 * (r16 & 1)) ^ (r16 >> 2)) << 3);
        #pragma unroll
        for (int tr = 0; tr < 2; ++tr) {
            #pragma unroll
            for (int v = 0; v < 4; ++v) {
                const int rowv = (tr * 16 + g * 4 + v) * PITCH;
                unsigned h0, l0, h1, l1, h2, l2, h3, l3;
                split2(acc1[0][tr][v], acc1[1][tr][v], h0, l0);
                split2(acc1[2][tr][v], acc1[3][tr][v], h1, l1);
                split2(acc1[4][tr][v], acc1[5][tr][v], h2, l2);
                split2(acc1[6][tr][v], acc1[7][tr][v], h3, l3);
                *(uint4*)(hiP + rowv + Cw) = make_uint4(h0, h1, h2, h3);
                *(uint4*)(loP + rowv + Cw) = make_uint4(l0, l1, l2, l3);
            }
        }
    }
    __syncthreads();

    // ---- phase 2: monarch stage 2, operand-swapped: h2^T = L^T @ mid^T ----
    f32x4 acc2[8][2];
    #pragma unroll
    for (int ci = 0; ci < 8; ++ci) {
        const int c = grp * 8 + ci;
        const unsigned short* wb = wpk + (size_t)(16 + c) * 8192;
        bf16x8 Wh0 = *(const bf16x8*)(wb + ((0*4+ntw)*2+0)*512 + lane*8);
        bf16x8 Wl0 = *(const bf16x8*)(wb + ((0*4+ntw)*2+1)*512 + lane*8);
        bf16x8 Wh1 = *(const bf16x8*)(wb + ((1*4+ntw)*2+0)*512 + lane*8);
        bf16x8 Wl1 = *(const bf16x8*)(wb + ((1*4+ntw)*2+1)*512 + lane*8);
        const int gx = ((g ^ (c & 3)) << 3);               // XOR swizzle (read)
        #pragma unroll
        for (int tr = 0; tr < 2; ++tr) {
            const int c0 = (tr * 16 + r16) * PITCH + c * 64 + gx;
            bf16x8 Hh0 = *(const bf16x8*)(hiP + c0);
            bf16x8 Hl0 = *(const bf16x8*)(loP + c0);
            bf16x8 Hh1 = *(const bf16x8*)(hiP + c0 + 32);
            bf16x8 Hl1 = *(const bf16x8*)(loP + c0 + 32);
            f32x4 a = {0.f, 0.f, 0.f, 0.f};
            a = MFMA(Wh0, Hh0, a); a = MFMA(Wh0, Hl0, a); a = MFMA(Wl0, Hh0, a);
            a = MFMA(Wh1, Hh1, a); a = MFMA(Wh1, Hl1, a); a = MFMA(Wl1, Hh1, a);
            acc2[ci][tr] = a;
        }
    }
    __syncthreads();   // all permuted-tile reads complete before overwrite

    // epilogue: +bias, write RAW h (hi/lo), LN partial sums
    {
        #pragma unroll
        for (int tr = 0; tr < 2; ++tr) {
            const int rowA = (tr * 16 + r16) * PITCH;
            float s = 0.f, s2 = 0.f;
            #pragma unroll
            for (int ci = 0; ci < 8; ++ci) {
                const int c = grp * 8 + ci;
                const int ncol = c * 64 + ntw * 16 + g * 4;
                const float4 bv = *(const float4*)(bias + ncol);
                const float f0 = acc2[ci][tr][0] + bv.x;
                const float f1 = acc2[ci][tr][1] + bv.y;
                const float f2 = acc2[ci][tr][2] + bv.z;
                const float f3 = acc2[ci][tr][3] + bv.w;
                s += f0 + f1 + f2 + f3;
                s2 += f0 * f0 + f1 * f1 + f2 * f2 + f3 * f3;
                unsigned hA, lA, hB, lB;
                split2(f0, f1, hA, lA);
                split2(f2, f3, hB, lB);
                *(uint2*)(hiP + rowA + ncol) = make_uint2(hA, hB);
                *(uint2*)(loP + rowA + ncol) = make_uint2(lA, lB);
            }
            s  += __shfl_xor(s, 16);  s  += __shfl_xor(s, 32);
            s2 += __shfl_xor(s2, 16); s2 += __shfl_xor(s2, 32);
            if (g == 0) {
                const int e = ((wave * 2 + tr) * 16 + r16) * 2;
                lnpart[e] = s; lnpart[e + 1] = s2;
            }
        }
    }
    __syncthreads();

    // ---- phase 4: down-proj on RAW h, swapped: d^T = Wd'^T @ h^T (hi-only);
    //      first 32 lanes also finish the LN stats reduce.
    if (tid < 32) {
        float s = 0.f, s2 = 0.f;
        #pragma unroll
        for (int w = 0; w < 8; ++w) {
            const int e = ((w * 2 + (tid >> 4)) * 16 + (tid & 15)) * 2;
            s += lnpart[e]; s2 += lnpart[e + 1];
        }
        const float mu = s * (1.f / 1024.f);
        statsR[tid * 2]     = mu;
        statsR[tid * 2 + 1] = rsqrtf(s2 * (1.f / 1024.f) - mu * mu + 1e-5f);
    }
    {
        f32x4 accd[2] = {{0.f,0.f,0.f,0.f}, {0.f,0.f,0.f,0.f}};
        #pragma unroll
        for (int ki = 0; ki < 16; ++ki) {
            const int kq = grp * 16 + ki;
            const int kb = kq >> 1, kin = kq & 1;
            const unsigned short* wb = wpk + (size_t)(32 + kb) * 8192;
            bf16x8 Wh = *(const bf16x8*)(wb + ((kin*4+ntw)*2+0)*512 + lane*8);
            #pragma unroll
            for (int tr = 0; tr < 2; ++tr) {
                bf16x8 Hh = *(const bf16x8*)(hiP + (tr*16 + r16)*PITCH + kq*32 + g*8);
                accd[tr] = MFMA(Wh, Hh, accd[tr]);
            }
        }
        #pragma unroll
        for (int tr = 0; tr < 2; ++tr)
            *(f32x4*)(dbuf + (grp * 32 + tr * 16 + r16) * DPITCH + ntw * 16 + g * 4) = accd[tr];
    }
    __syncthreads();

    // ---- phase 5: LN-fixup + up-proj + residual + sin/cos + final linear ----
    const float* bcf = (const float*)(wpk + (size_t)64 * 8192);
    float muT[2], rsT[2], muR[2][4], rsR[2][4];
    #pragma unroll
    for (int tr = 0; tr < 2; ++tr) {
        muT[tr] = statsR[(tr * 16 + r16) * 2];
        rsT[tr] = statsR[(tr * 16 + r16) * 2 + 1];
        #pragma unroll
        for (int v = 0; v < 4; ++v) {
            muR[tr][v] = statsR[(tr * 16 + g * 4 + v) * 2];
            rsR[tr][v] = statsR[(tr * 16 + g * 4 + v) * 2 + 1];
        }
    }
    bf16x8 dA[2][2];
    #pragma unroll
    for (int kk = 0; kk < 2; ++kk) {
        const int rb = kk * 32 + g * 8;
        const float4 B0 = *(const float4*)(bcf + rb);
        const float4 B1 = *(const float4*)(bcf + rb + 4);
        const float4 C0 = *(const float4*)(bcf + 64 + rb);
        const float4 C1 = *(const float4*)(bcf + 64 + rb + 4);
        const float Ba[8] = {B0.x,B0.y,B0.z,B0.w,B1.x,B1.y,B1.z,B1.w};
        const float Ca[8] = {C0.x,C0.y,C0.z,C0.w,C1.x,C1.y,C1.z,C1.w};
        #pragma unroll
        for (int tr = 0; tr < 2; ++tr) {
            const int di = (tr * 16 + r16) * DPITCH + rb;
            const f32x4 q0 = *(const f32x4*)(dbuf + di);
            const f32x4 q1 = *(const f32x4*)(dbuf + di + 4);
            const f32x4 p0 = *(const f32x4*)(dbuf + TOK * DPITCH + di);
            const f32x4 p1 = *(const f32x4*)(dbuf + TOK * DPITCH + di + 4);
            float dv[8];
            #pragma unroll
            for (int v = 0; v < 4; ++v) {
                dv[v]     = rsT[tr] * (q0[v] + p0[v]) - muT[tr] * rsT[tr] * Ba[v]     + Ca[v];
                dv[v + 4] = rsT[tr] * (q1[v] + p1[v]) - muT[tr] * rsT[tr] * Ba[v + 4] + Ca[v + 4];
            }
            const unsigned u0 = cvt_pk_bf16(dv[0], dv[1]);
            const unsigned u1 = cvt_pk_bf16(dv[2], dv[3]);
            const unsigned u2 = cvt_pk_bf16(dv[4], dv[5]);
            const unsigned u3 = cvt_pk_bf16(dv[6], dv[7]);
            uint4 uu = make_uint4(u0, u1, u2, u3);
            dA[tr][kk] = *(bf16x8*)&uu;
        }
    }
    float wp[24];
    #pragma unroll
    for (int k2 = 0; k2 < 24; ++k2) wp[k2] = Wp[k2];
    const float bp0 = bpv[0], bp1 = bpv[1], bp2 = bpv[2], bp3 = bpv[3];

    #pragma unroll 1
    for (int j = 0; j < 8; ++j) {
        const int ntg = wave * 8 + j;
        const int nb = ntg >> 2, ntin = ntg & 3;
        const unsigned short* wb = wpk + (size_t)(48 + nb) * 8192;
        bf16x8 Bh0 = *(const bf16x8*)(wb + ((0*4+ntin)*2+0)*512 + lane*8);
        bf16x8 Bh1 = *(const bf16x8*)(wb + ((1*4+ntin)*2+0)*512 + lane*8);
        const int p = ntg * 16 + r16;
        const float4 t0 = *(const float4*)(bcf + 128 + p * 8);
        const float4 t1 = *(const float4*)(bcf + 128 + p * 8 + 4);
        const float gp = t0.x, bpp = t0.y;
        const float th0 = t0.z, th1 = t0.w, th2 = t1.x;
        const float ph0 = t1.y, ph1 = t1.z, ph2 = t1.w;
        #pragma unroll
        for (int tr = 0; tr < 2; ++tr) {
            f32x4 au = {0.f, 0.f, 0.f, 0.f};
            au = MFMA(dA[tr][0], Bh0, au);
            au = MFMA(dA[tr][1], Bh1, au);
            #pragma unroll
            for (int v = 0; v < 4; ++v) {
                const int row = tr * 16 + g * 4 + v;
                const float hraw = bf2f(hiP[row * PITCH + p]) + bf2f(loP[row * PITCH + p]);
                const float hn = (hraw - muR[tr][v]) * rsR[tr][v] * gp + bpp;
                const float e = au[v] + hn;
                float o0 = bp0, o1 = bp1, o2 = bp2, o3 = bp3;
                float arg, sn, cs;
                asm("v_fract_f32 %0, %1" : "=v"(arg) : "v"(fmaf(e, th0, ph0)));
                asm("v_sin_f32 %0, %1" : "=v"(sn) : "v"(arg));
                asm("v_cos_f32 %0, %1" : "=v"(cs) : "v"(arg));
                o0 = fmaf(sn, wp[0],  fmaf(cs, wp[1],  o0));
                o1 = fmaf(sn, wp[6],  fmaf(cs, wp[7],  o1));
                o2 = fmaf(sn, wp[12], fmaf(cs, wp[13], o2));
                o3 = fmaf(sn, wp[18], fmaf(cs, wp[19], o3));
                asm("v_fract_f32 %0, %1" : "=v"(arg) : "v"(fmaf(e, th1, ph1)));
                asm("v_sin_f32 %0, %1" : "=v"(sn) : "v"(arg));
                asm("v_cos_f32 %0, %1" : "=v"(cs) : "v"(arg));
                o0 = fmaf(sn, wp[2],  fmaf(cs, wp[3],  o0));
                o1 = fmaf(sn, wp[8],  fmaf(cs, wp[9],  o1));
                o2 = fmaf(sn, wp[14], fmaf(cs, wp[15], o2));
                o3 = fmaf(sn, wp[20], fmaf(cs, wp[21], o3));
                asm("v_fract_f32 %0, %1" : "=v"(arg) : "v"(fmaf(e, th2, ph2)));
                asm("v_sin_f32 %0, %1" : "=v"(sn) : "v"(arg));
                asm("v_cos_f32 %0, %1" : "=v"(cs) : "v"(arg));
                o0 = fmaf(sn, wp[4],  fmaf(cs, wp[5],  o0));
                o1 = fmaf(sn, wp[10], fmaf(cs, wp[11], o1));
                o2 = fmaf(sn, wp[16], fmaf(cs, wp[17], o2));
                o3 = fmaf(sn, wp[22], fmaf(cs, wp[23], o3));
                *(float4*)(out + ((n0 + row) * 1024 + p) * 4) = make_float4(o0, o1, o2, o3);
            }
        }
    }
}

extern "C" void kernel_launch(void* const* d_in, const int* in_sizes, int n_in,
                              void* d_out, int out_size, void* d_ws, size_t ws_size,
                              hipStream_t stream) {
    const float* x      = (const float*)d_in[0];
    const float* R      = (const float*)d_in[1];
    const float* L      = (const float*)d_in[2];
    const float* bias   = (const float*)d_in[3];
    const float* gamma  = (const float*)d_in[4];
    const float* beta   = (const float*)d_in[5];
    const float* Wd     = (const float*)d_in[6];
    const float* Wu     = (const float*)d_in[7];
    const float* thetas = (const float*)d_in[8];
    const float* phis   = (const float*)d_in[9];
    const float* Wp     = (const float*)d_in[10];
    const float* bp     = (const float*)d_in[11];
    float* out = (float*)d_out;
    unsigned short* wsp = (unsigned short*)d_ws;
    const int N = in_sizes[0] / 1024;   // 8192 tokens

    (void)hipFuncSetAttribute((const void*)qrun_main,
                              hipFuncAttributeMaxDynamicSharedMemorySize, SMEM_BYTES);
    pack_weights<<<dim3(65), dim3(256), 0, stream>>>(R, L, Wd, Wu, gamma, beta,
                                                     thetas, phis, wsp);
    qrun_main<<<dim3(N / TOK), dim3(512), SMEM_BYTES, stream>>>(
        x, bias, Wp, bp, wsp, out);
}

// Round 6
// 61.252 us; speedup vs baseline: 1.0448x; 1.0448x over previous
//
#include <hip/hip_runtime.h>

// Q_RUNLayer_Hybrid: monarch(blockdiag R -> stride perm -> blockdiag L) + bias
// -> LayerNorm -> h + (h@Wd)@Wu -> sin/cos reupload (3) -> [PROJ,6]@Wp.T+bp
// Fused MFMA, 16 tokens/wg, R3 phase skeleton (LDS-staged x) + proven levers:
// split-bf16 via v_cvt_pk_bf16_f32, LayerNorm folded into down-proj
// (Wd' = diag(gamma)Wd; fixup B=gamma@Wd, C=beta@Wd), packed per-p param
// table with 1/(2pi)-folded thetas/phis for v_fract/v_sin/v_cos.

typedef __attribute__((ext_vector_type(8))) short bf16x8;
typedef __attribute__((ext_vector_type(4))) float f32x4;

#define PITCH 1032            // ushorts per plane row (1024 + 8 pad)
#define DPITCH 68             // floats per dbuf row
#define DHALF (16 * DPITCH)   // 1088
#define SMEM_BYTES 75904      // 2*16*1032*2 + 2*1088*4 + 256*4 + 32*4

__device__ __forceinline__ unsigned short f2bf(float f) {
    unsigned u = __float_as_uint(f);
    u = (u + 0x7FFFu + ((u >> 16) & 1u)) >> 16;   // RNE f32 -> bf16
    return (unsigned short)u;
}
__device__ __forceinline__ float bf2f(unsigned short h) {
    return __uint_as_float(((unsigned)h) << 16);
}
__device__ __forceinline__ unsigned cvt_pk_bf16(float a, float b) {
    unsigned r;                                   // lo16 = bf16(a), hi16 = bf16(b)
    asm("v_cvt_pk_bf16_f32 %0, %1, %2" : "=v"(r) : "v"(a), "v"(b));
    return r;
}
// split (a,b) -> packed hi u32 + packed lo u32 (lo = exact residual, re-rounded)
__device__ __forceinline__ void split2(float a, float b, unsigned &H, unsigned &L) {
    H = cvt_pk_bf16(a, b);
    const float ha = __uint_as_float(H << 16);
    const float hb = __uint_as_float(H & 0xFFFF0000u);
    L = cvt_pk_bf16(a - ha, b - hb);
}
__device__ __forceinline__ f32x4 MFMA(bf16x8 a, bf16x8 b, f32x4 c) {
    return __builtin_amdgcn_mfma_f32_16x16x32_bf16(a, b, c, 0, 0, 0);
}

// ---------------------------------------------------------------------------
// Pack weights into MFMA fragment order (hi/lo bf16). 257 wgs: wg (blk*4+it)
// packs quarter `it` of 64x64 block `blk`; wg 256 computes the fixup/param
// table. blk 0..15 = R[b], 16..31 = L[c], 32..47 = Wd' = diag(gamma)Wd,
// 48..63 = Wu. Table at float offset 64*8192 ushorts:
//   bcf[0..63] = B = gamma@Wd, bcf[64..127] = C = beta@Wd,
//   bcf[128 + p*8 + {0..7}] = {gamma, beta, th0',th1',th2', ph0',ph1',ph2'}
//   with th'/ph' pre-multiplied by 1/(2*pi)  (for v_sin/v_cos).
// Frag addressing (ushorts): blk*8192 + ((kk*4+nt)*2+comp)*512 + lane*8
// element v of lane l:  M[kk*32 + (l>>4)*8 + v][nt*16 + (l&15)]
// ---------------------------------------------------------------------------
__global__ __launch_bounds__(256) void pack_weights(
    const float* __restrict__ R, const float* __restrict__ L,
    const float* __restrict__ Wd, const float* __restrict__ Wu,
    const float* __restrict__ gamma, const float* __restrict__ beta,
    const float* __restrict__ thetas, const float* __restrict__ phis,
    unsigned short* __restrict__ wsp)
{
    const int bx = blockIdx.x;
    const int tid = threadIdx.x;
    if (bx == 256) {
        float* bc = (float*)(wsp + (size_t)64 * 8192);
        const float INV2PI = 0.15915494309189535f;
        for (int i = tid; i < 1024; i += 256) {
            float* t = bc + 128 + i * 8;
            t[0] = gamma[i];                 t[1] = beta[i];
            t[2] = thetas[i] * INV2PI;       t[3] = thetas[1024 + i] * INV2PI;
            t[4] = thetas[2048 + i] * INV2PI;
            t[5] = phis[i] * INV2PI;         t[6] = phis[1024 + i] * INV2PI;
            t[7] = phis[2048 + i] * INV2PI;
        }
        __shared__ float red[8][64];
        const int r = tid & 63, part = tid >> 6;
        float sb = 0.f, sc = 0.f;
        for (int c = part * 256; c < part * 256 + 256; ++c) {
            const float w = Wd[(size_t)c * 64 + r];
            sb += gamma[c] * w;
            sc += beta[c] * w;
        }
        red[part][r] = sb; red[part + 4][r] = sc;
        __syncthreads();
        if (part == 0) {
            bc[r]      = red[0][r] + red[1][r] + red[2][r] + red[3][r];
            bc[64 + r] = red[4][r] + red[5][r] + red[6][r] + red[7][r];
        }
        return;
    }
    const int blk = bx >> 2;
    unsigned short* dst = wsp + (size_t)blk * 8192;
    const int slot = tid + (bx & 3) * 256;     // 0..1023
    const int fragidx = slot >> 6;             // 0..15
    const int l = slot & 63;
    const int kk = fragidx >> 3;
    const int nt = (fragidx >> 1) & 3;
    const int comp = fragidx & 1;
    const int g = l >> 4, r16 = l & 15;
    const int j = nt * 16 + r16;
    bf16x8 s;
    #pragma unroll
    for (int v = 0; v < 8; ++v) {
        const int k = kk * 32 + g * 8 + v;
        float w;
        if (blk < 16)      w = R[(size_t)blk * 4096 + k * 64 + j];
        else if (blk < 32) w = L[(size_t)(blk - 16) * 4096 + k * 64 + j];
        else if (blk < 48) {
            const int kglob = (blk - 32) * 64 + k;
            w = gamma[kglob] * Wd[(size_t)kglob * 64 + j];
        } else             w = Wu[(size_t)k * 1024 + (blk - 48) * 64 + j];
        unsigned short hi = f2bf(w);
        unsigned short bits = (comp == 0) ? hi : f2bf(w - bf2f(hi));
        s[v] = (short)bits;
    }
    *(bf16x8*)(dst + fragidx * 512 + l * 8) = s;
}

// ---------------------------------------------------------------------------
// Fused main kernel. 512 threads (8 waves), 16 tokens per workgroup.
// Wave w: grp = w>>2 (splits block/K loops), ntw = w&3 (16-col subtile).
// ---------------------------------------------------------------------------
__global__ __launch_bounds__(512, 4) void qrun_main(
    const float* __restrict__ x, const float* __restrict__ bias,
    const float* __restrict__ Wp, const float* __restrict__ bpv,
    const unsigned short* __restrict__ wpk, float* __restrict__ out)
{
    extern __shared__ char smem[];
    unsigned short* hiP = (unsigned short*)smem;          // [16][PITCH]
    unsigned short* loP = hiP + 16 * PITCH;               // [16][PITCH]
    float* dbuf = (float*)(loP + 16 * PITCH);             // [2][16][DPITCH]
    float* lnpart = dbuf + 2 * DHALF;                     // [8][16][2]
    float* statsR = lnpart + 256;                         // [16][2]

    const int tid = threadIdx.x;
    const int wave = tid >> 6, lane = tid & 63;
    const int g = lane >> 4, r16 = lane & 15;
    const int grp = wave >> 2, ntw = wave & 3;
    const size_t n0 = (size_t)blockIdx.x * 16;
    const int rowA = r16 * PITCH;

    // ---- phase 0: load x tile, split to hi/lo bf16 planes ----
    {
        const float* xb = x + n0 * 1024;
        #pragma unroll
        for (int it = 0; it < 4; ++it) {
            const int base = (it * 512 + tid) * 8;
            const int row = base >> 10, col = base & 1023;
            const float4 f0 = *(const float4*)(xb + base);
            const float4 f1 = *(const float4*)(xb + base + 4);
            unsigned H0, L0, H1, L1, H2, L2, H3, L3;
            split2(f0.x, f0.y, H0, L0);
            split2(f0.z, f0.w, H1, L1);
            split2(f1.x, f1.y, H2, L2);
            split2(f1.z, f1.w, H3, L3);
            *(uint4*)(hiP + row * PITCH + col) = make_uint4(H0, H1, H2, H3);
            *(uint4*)(loP + row * PITCH + col) = make_uint4(L0, L1, L2, L3);
        }
    }
    __syncthreads();

    // ---- phase 1: monarch stage 1 (x @ R[b]); reads all -> barrier -> writes ----
    f32x4 acc1[8];
    #pragma unroll
    for (int bi = 0; bi < 8; ++bi) {
        const int b = grp * 8 + bi;
        const unsigned short* wb = wpk + (size_t)b * 8192;
        bf16x8 Bh0 = *(const bf16x8*)(wb + ((0*4+ntw)*2+0)*512 + lane*8);
        bf16x8 Bl0 = *(const bf16x8*)(wb + ((0*4+ntw)*2+1)*512 + lane*8);
        bf16x8 Bh1 = *(const bf16x8*)(wb + ((1*4+ntw)*2+0)*512 + lane*8);
        bf16x8 Bl1 = *(const bf16x8*)(wb + ((1*4+ntw)*2+1)*512 + lane*8);
        const int ca = b * 64 + g * 8;
        bf16x8 Ah0 = *(const bf16x8*)(hiP + rowA + ca);
        bf16x8 Al0 = *(const bf16x8*)(loP + rowA + ca);
        bf16x8 Ah1 = *(const bf16x8*)(hiP + rowA + ca + 32);
        bf16x8 Al1 = *(const bf16x8*)(loP + rowA + ca + 32);
        f32x4 a = {0.f, 0.f, 0.f, 0.f};
        a = MFMA(Ah0, Bh0, a); a = MFMA(Ah0, Bl0, a); a = MFMA(Al0, Bh0, a);
        a = MFMA(Ah1, Bh1, a); a = MFMA(Ah1, Bl1, a); a = MFMA(Al1, Bh1, a);
        acc1[bi] = a;
    }
    __syncthreads();   // all stage-1 reads complete before permuted overwrite

    // permuted write: D col (b*64+ntw*16+r16) -> dest col; the 8 bi land on 8
    // consecutive columns => uint4 write. g-field XOR-swizzled by (c'&3).
    {
        const int Cw = (ntw * 4 + (r16 >> 2)) * 64 + ((r16 >> 1) & 1) * 32
                     + (((grp + 2 * (r16 & 1)) ^ (r16 >> 2)) << 3);
        #pragma unroll
        for (int v = 0; v < 4; ++v) {
            const int rowv = (g * 4 + v) * PITCH;
            unsigned h0, l0, h1, l1, h2, l2, h3, l3;
            split2(acc1[0][v], acc1[1][v], h0, l0);
            split2(acc1[2][v], acc1[3][v], h1, l1);
            split2(acc1[4][v], acc1[5][v], h2, l2);
            split2(acc1[6][v], acc1[7][v], h3, l3);
            *(uint4*)(hiP + rowv + Cw) = make_uint4(h0, h1, h2, h3);
            *(uint4*)(loP + rowv + Cw) = make_uint4(l0, l1, l2, l3);
        }
    }
    __syncthreads();

    // ---- phase 2: monarch stage 2, operand-swapped: h2^T = L^T @ mid^T ----
    f32x4 acc2[8];
    #pragma unroll
    for (int ci = 0; ci < 8; ++ci) {
        const int c = grp * 8 + ci;
        const unsigned short* wb = wpk + (size_t)(16 + c) * 8192;
        bf16x8 Wh0 = *(const bf16x8*)(wb + ((0*4+ntw)*2+0)*512 + lane*8);
        bf16x8 Wl0 = *(const bf16x8*)(wb + ((0*4+ntw)*2+1)*512 + lane*8);
        bf16x8 Wh1 = *(const bf16x8*)(wb + ((1*4+ntw)*2+0)*512 + lane*8);
        bf16x8 Wl1 = *(const bf16x8*)(wb + ((1*4+ntw)*2+1)*512 + lane*8);
        const int gx = ((g ^ (c & 3)) << 3);               // XOR swizzle (read)
        const int c0 = rowA + c * 64 + gx;                 // kk=0
        bf16x8 Hh0 = *(const bf16x8*)(hiP + c0);
        bf16x8 Hl0 = *(const bf16x8*)(loP + c0);
        bf16x8 Hh1 = *(const bf16x8*)(hiP + c0 + 32);
        bf16x8 Hl1 = *(const bf16x8*)(loP + c0 + 32);
        f32x4 a = {0.f, 0.f, 0.f, 0.f};
        a = MFMA(Wh0, Hh0, a); a = MFMA(Wh0, Hl0, a); a = MFMA(Wl0, Hh0, a);
        a = MFMA(Wh1, Hh1, a); a = MFMA(Wh1, Hl1, a); a = MFMA(Wl1, Hh1, a);
        acc2[ci] = a;
    }
    __syncthreads();   // all permuted-tile reads complete before overwrite

    // epilogue: +bias, write RAW h (hi/lo), LN partial sums
    {
        float s = 0.f, s2 = 0.f;
        #pragma unroll
        for (int ci = 0; ci < 8; ++ci) {
            const int c = grp * 8 + ci;
            const int ncol = c * 64 + ntw * 16 + g * 4;
            const float4 bv = *(const float4*)(bias + ncol);
            const float f0 = acc2[ci][0] + bv.x;
            const float f1 = acc2[ci][1] + bv.y;
            const float f2 = acc2[ci][2] + bv.z;
            const float f3 = acc2[ci][3] + bv.w;
            s += f0 + f1 + f2 + f3;
            s2 += f0 * f0 + f1 * f1 + f2 * f2 + f3 * f3;
            unsigned hA, lA, hB, lB;
            split2(f0, f1, hA, lA);
            split2(f2, f3, hB, lB);
            *(uint2*)(hiP + rowA + ncol) = make_uint2(hA, hB);
            *(uint2*)(loP + rowA + ncol) = make_uint2(lA, lB);
        }
        s  += __shfl_xor(s, 16);  s  += __shfl_xor(s, 32);
        s2 += __shfl_xor(s2, 16); s2 += __shfl_xor(s2, 32);
        if (g == 0) {
            lnpart[(wave * 16 + r16) * 2]     = s;
            lnpart[(wave * 16 + r16) * 2 + 1] = s2;
        }
    }
    __syncthreads();

    // ---- phase 4: down-proj on RAW h, swapped: d^T = Wd'^T @ h^T (hi-only);
    //      first 16 lanes also finish the LN stats reduce.
    if (tid < 16) {
        float s = 0.f, s2 = 0.f;
        #pragma unroll
        for (int w = 0; w < 8; ++w) {
            s  += lnpart[(w * 16 + tid) * 2];
            s2 += lnpart[(w * 16 + tid) * 2 + 1];
        }
        const float mu = s * (1.f / 1024.f);
        statsR[tid * 2]     = mu;
        statsR[tid * 2 + 1] = rsqrtf(s2 * (1.f / 1024.f) - mu * mu + 1e-5f);
    }
    {
        f32x4 accd = {0.f, 0.f, 0.f, 0.f};
        #pragma unroll
        for (int ki = 0; ki < 16; ++ki) {
            const int kq = grp * 16 + ki;
            const int kb = kq >> 1, kin = kq & 1;
            const unsigned short* wb = wpk + (size_t)(32 + kb) * 8192;
            bf16x8 Wh = *(const bf16x8*)(wb + ((kin*4+ntw)*2+0)*512 + lane*8);
            bf16x8 Hh = *(const bf16x8*)(hiP + rowA + kq * 32 + g * 8);
            accd = MFMA(Wh, Hh, accd);
        }
        // D[rank-local g*4+v][token r16]; rank r = ntw*16 + g*4 + v
        *(f32x4*)(dbuf + grp * DHALF + r16 * DPITCH + ntw * 16 + g * 4) = accd;
    }
    __syncthreads();

    // ---- phase 5: LN-fixup + up-proj + residual + sin/cos + final linear ----
    const float* bcf = (const float*)(wpk + (size_t)64 * 8192);
    const float muT = statsR[r16 * 2], rsT = statsR[r16 * 2 + 1];
    float muR[4], rsR[4];
    #pragma unroll
    for (int v = 0; v < 4; ++v) {
        muR[v] = statsR[(g * 4 + v) * 2];
        rsR[v] = statsR[(g * 4 + v) * 2 + 1];
    }
    bf16x8 dA[2];
    #pragma unroll
    for (int kk = 0; kk < 2; ++kk) {
        const int rb = kk * 32 + g * 8;
        const float4 B0 = *(const float4*)(bcf + rb);
        const float4 B1 = *(const float4*)(bcf + rb + 4);
        const float4 C0 = *(const float4*)(bcf + 64 + rb);
        const float4 C1 = *(const float4*)(bcf + 64 + rb + 4);
        const float Ba[8] = {B0.x,B0.y,B0.z,B0.w,B1.x,B1.y,B1.z,B1.w};
        const float Ca[8] = {C0.x,C0.y,C0.z,C0.w,C1.x,C1.y,C1.z,C1.w};
        const int di = r16 * DPITCH + rb;
        const f32x4 q0 = *(const f32x4*)(dbuf + di);
        const f32x4 q1 = *(const f32x4*)(dbuf + di + 4);
        const f32x4 p0 = *(const f32x4*)(dbuf + DHALF + di);
        const f32x4 p1 = *(const f32x4*)(dbuf + DHALF + di + 4);
        float dv[8];
        #pragma unroll
        for (int v = 0; v < 4; ++v) {
            dv[v]     = rsT * (q0[v] + p0[v]) - muT * rsT * Ba[v]     + Ca[v];
            dv[v + 4] = rsT * (q1[v] + p1[v]) - muT * rsT * Ba[v + 4] + Ca[v + 4];
        }
        const uint4 uu = make_uint4(cvt_pk_bf16(dv[0], dv[1]),
                                    cvt_pk_bf16(dv[2], dv[3]),
                                    cvt_pk_bf16(dv[4], dv[5]),
                                    cvt_pk_bf16(dv[6], dv[7]));
        dA[kk] = __builtin_bit_cast(bf16x8, uu);
    }
    float wp[24];
    #pragma unroll
    for (int k2 = 0; k2 < 24; ++k2) wp[k2] = Wp[k2];
    const float bp0 = bpv[0], bp1 = bpv[1], bp2 = bpv[2], bp3 = bpv[3];

    #pragma unroll 1
    for (int j = 0; j < 8; ++j) {
        const int ntg = wave * 8 + j;
        const int nb = ntg >> 2, ntin = ntg & 3;
        const unsigned short* wb = wpk + (size_t)(48 + nb) * 8192;
        bf16x8 Bh0 = *(const bf16x8*)(wb + ((0*4+ntin)*2+0)*512 + lane*8);
        bf16x8 Bh1 = *(const bf16x8*)(wb + ((1*4+ntin)*2+0)*512 + lane*8);
        f32x4 au = {0.f, 0.f, 0.f, 0.f};
        au = MFMA(dA[0], Bh0, au);
        au = MFMA(dA[1], Bh1, au);
        const int p = ntg * 16 + r16;
        const float4 t0 = *(const float4*)(bcf + 128 + p * 8);
        const float4 t1 = *(const float4*)(bcf + 128 + p * 8 + 4);
        const float gp = t0.x, bpp = t0.y;
        const float th0 = t0.z, th1 = t0.w, th2 = t1.x;
        const float ph0 = t1.y, ph1 = t1.z, ph2 = t1.w;
        #pragma unroll
        for (int v = 0; v < 4; ++v) {
            const int row = g * 4 + v;
            const float hraw = bf2f(hiP[row * PITCH + p]) + bf2f(loP[row * PITCH + p]);
            const float hn = (hraw - muR[v]) * rsR[v] * gp + bpp;
            const float e = au[v] + hn;
            float o0 = bp0, o1 = bp1, o2 = bp2, o3 = bp3;
            float arg, sn, cs;
            asm("v_fract_f32 %0, %1" : "=v"(arg) : "v"(fmaf(e, th0, ph0)));
            asm("v_sin_f32 %0, %1" : "=v"(sn) : "v"(arg));
            asm("v_cos_f32 %0, %1" : "=v"(cs) : "v"(arg));
            o0 = fmaf(sn, wp[0],  fmaf(cs, wp[1],  o0));
            o1 = fmaf(sn, wp[6],  fmaf(cs, wp[7],  o1));
            o2 = fmaf(sn, wp[12], fmaf(cs, wp[13], o2));
            o3 = fmaf(sn, wp[18], fmaf(cs, wp[19], o3));
            asm("v_fract_f32 %0, %1" : "=v"(arg) : "v"(fmaf(e, th1, ph1)));
            asm("v_sin_f32 %0, %1" : "=v"(sn) : "v"(arg));
            asm("v_cos_f32 %0, %1" : "=v"(cs) : "v"(arg));
            o0 = fmaf(sn, wp[2],  fmaf(cs, wp[3],  o0));
            o1 = fmaf(sn, wp[8],  fmaf(cs, wp[9],  o1));
            o2 = fmaf(sn, wp[14], fmaf(cs, wp[15], o2));
            o3 = fmaf(sn, wp[20], fmaf(cs, wp[21], o3));
            asm("v_fract_f32 %0, %1" : "=v"(arg) : "v"(fmaf(e, th2, ph2)));
            asm("v_sin_f32 %0, %1" : "=v"(sn) : "v"(arg));
            asm("v_cos_f32 %0, %1" : "=v"(cs) : "v"(arg));
            o0 = fmaf(sn, wp[4],  fmaf(cs, wp[5],  o0));
            o1 = fmaf(sn, wp[10], fmaf(cs, wp[11], o1));
            o2 = fmaf(sn, wp[16], fmaf(cs, wp[17], o2));
            o3 = fmaf(sn, wp[22], fmaf(cs, wp[23], o3));
            *(float4*)(out + ((n0 + row) * 1024 + p) * 4) = make_float4(o0, o1, o2, o3);
        }
    }
}

extern "C" void kernel_launch(void* const* d_in, const int* in_sizes, int n_in,
                              void* d_out, int out_size, void* d_ws, size_t ws_size,
                              hipStream_t stream) {
    const float* x      = (const float*)d_in[0];
    const float* R      = (const float*)d_in[1];
    const float* L      = (const float*)d_in[2];
    const float* bias   = (const float*)d_in[3];
    const float* gamma  = (const float*)d_in[4];
    const float* beta   = (const float*)d_in[5];
    const float* Wd     = (const float*)d_in[6];
    const float* Wu     = (const float*)d_in[7];
    const float* thetas = (const float*)d_in[8];
    const float* phis   = (const float*)d_in[9];
    const float* Wp     = (const float*)d_in[10];
    const float* bp     = (const float*)d_in[11];
    float* out = (float*)d_out;
    unsigned short* wsp = (unsigned short*)d_ws;
    const int N = in_sizes[0] / 1024;   // 8192 tokens

    (void)hipFuncSetAttribute((const void*)qrun_main,
                              hipFuncAttributeMaxDynamicSharedMemorySize, SMEM_BYTES);
    pack_weights<<<dim3(257), dim3(256), 0, stream>>>(R, L, Wd, Wu, gamma, beta,
                                                      thetas, phis, wsp);
    qrun_main<<<dim3(N / 16), dim3(512), SMEM_BYTES, stream>>>(
        x, bias, Wp, bp, wsp, out);
}